// Round 7
// baseline (278.178 us; speedup 1.0000x reference)
//
#include <hip/hip_runtime.h>

// ============================================================================
// global_conv_attn: B=4, C=H=O=256, N=4096, GROUPS=32
//
// Pipeline (all bf16-MFMA, fp32 accumulate), 4 launches:
//   prepT: weights fp32->bf16 (256 blocks) + x transpose (1024 blocks)
//          + zero split-group counters
//   gemm1: k/qT/v1 = xt * W^T + bias; q,v1 linear [b][n][h];
//          k stored CHUNK-TILED [b][nc][ks16][n32][h16] (16KB/chunk)
//   cg2  : FUSED conv+gemm2; v stored CHUNK-TILED [b][nc][kn2][o256][n16]
//   attn : flash, 32x32x16 MFMA, m32/wave (128 AGPR + 128 VGPR, 2 w/SIMD),
//          tiled layouts -> ds_read addr = lane_const + imm, dbuf
//          global_load_lds staging, constant-shift softmax,
//          P relayout via v_permlane32_swap (4 VALU ops, was 16 ds_bpermute),
//          FUSED split-combine: last block per (b,mt128) group merges the
//          4 n-splits (threadfence + device atomicAdd pattern).
//
// R6 post-mortem: attn LDS-pipe ~68% busy (reads 3072 + bpermute 770 +
// staging 600 cyc/CU-iter); occupancy reg-capped at 2 waves/SIMD. Non-attn
// ~170us stable since R1 -> launch/ramp overhead suspected. R7: move
// relayout off the LDS pipe, cut 6 launches -> 4.
//
// MFMA 32x32x16 layouts (gfx950):
//   A row=lane&31, k=(lane>>5)*8+j;  B col=lane&31, same k
//   D col=lane&31, row=(reg&3)+8*(reg>>2)+4*(lane>>5)   [D HW-verified]
// permlane32_swap(a,b): a' = {a[0:31], b[0:31]}, b' = {a[32:63], b[32:63]}
// ============================================================================

#define B_ 4
#define C_ 256
#define H_ 256
#define O_ 256
#define N_ 4096
#define NSPLIT 4
#define SPAN (N_ / NSPLIT)     // 1024
#define ITERS (SPAN / 32)      // 32

typedef short short8 __attribute__((ext_vector_type(8)));
typedef float floatx4 __attribute__((ext_vector_type(4)));
typedef float floatx16 __attribute__((ext_vector_type(16)));
typedef unsigned uint2v __attribute__((ext_vector_type(2)));

__device__ __forceinline__ unsigned short f2bf(float f) {
  unsigned u = __float_as_uint(f);
  u = (u + 0x7fffu + ((u >> 16) & 1u)) >> 16;   // RNE
  return (unsigned short)u;
}
__device__ __forceinline__ float bf2f(unsigned short u) {
  return __uint_as_float(((unsigned)u) << 16);
}
__device__ __forceinline__ floatx4 mfma16(short8 a, short8 b, floatx4 c) {
  return __builtin_amdgcn_mfma_f32_16x16x32_bf16(a, b, c, 0, 0, 0);
}
__device__ __forceinline__ floatx16 mfma32(short8 a, short8 b, floatx16 c) {
  return __builtin_amdgcn_mfma_f32_32x32x16_bf16(a, b, c, 0, 0, 0);
}
// pack two floats -> (bf16(a) | bf16(b)<<16), round-half-up (2 add + 1 perm)
__device__ __forceinline__ unsigned pack2bf(float a, float b) {
  return __builtin_amdgcn_perm(__float_as_uint(b) + 0x8000u,
                               __float_as_uint(a) + 0x8000u, 0x07060302u);
}

// ---------------------------------------------------------------------------
// merged prep (blocks 1024..1279) + transpose (blocks 0..1023) + cnt zero
__global__ __launch_bounds__(256) void prep_transpose_kernel(
    const float* __restrict__ x, unsigned short* __restrict__ xt,
    const float* __restrict__ Wk, const float* __restrict__ Wq,
    const float* __restrict__ W1, const float* __restrict__ W3,
    unsigned short* __restrict__ wk, unsigned short* __restrict__ wq,
    unsigned short* __restrict__ w1, unsigned short* __restrict__ w3,
    unsigned int* __restrict__ cnt) {
  __shared__ unsigned short tile[64][66];
  const int gid = blockIdx.x;     // 1280
  const int t = threadIdx.x;
  if (gid >= 1024) {              // weight prep
    const int i = (gid - 1024) * 256 + t;    // 65536
    wk[i] = f2bf(Wk[i]);
    wq[i] = f2bf(Wq[i]);
    w1[i] = f2bf(W1[i]);
    w3[i] = f2bf(W3[i]);
    if (gid == 1024 && t < 128) cnt[t] = 0u;
    return;
  }
  const int b  = gid >> 8;
  const int ct = (gid >> 6) & 3;
  const int nt = gid & 63;
  const int c0 = ct * 64, n0 = nt * 64;
  const float* xb = x + ((size_t)b * C_ + c0) * N_ + n0;
#pragma unroll
  for (int rr = 0; rr < 4; ++rr) {
    const int c = (t >> 4) + rr * 16;
    const floatx4 v = *reinterpret_cast<const floatx4*>(
        xb + (size_t)c * N_ + (t & 15) * 4);
#pragma unroll
    for (int i = 0; i < 4; ++i) tile[c][(t & 15) * 4 + i] = f2bf(v[i]);
  }
  __syncthreads();
  unsigned short* xo = xt + ((size_t)b * N_ + n0) * C_ + c0;
#pragma unroll
  for (int rr = 0; rr < 2; ++rr) {
    const int nr = (t >> 3) + rr * 32;
    short8 pk;
#pragma unroll
    for (int i = 0; i < 8; ++i) pk[i] = (short)tile[(t & 7) * 8 + i][nr];
    *reinterpret_cast<short8*>(xo + (size_t)nr * C_ + (t & 7) * 8) = pk;
  }
}

// ---------------------------------------------------------------------------
// gemm1: D[n][h] = sum_c xt[n][c] * W[h][c] + bias[h], for Wk,Wq,W1.
// k output -> chunk-tiled layout [b][n>>5][h>>4][n&31][h&15].
// Block waves share h-half -> W B-frags L1-resident across waves.
__global__ __launch_bounds__(256) void gemm1_kernel(
    const unsigned short* __restrict__ xt,
    const unsigned short* __restrict__ wk, const unsigned short* __restrict__ wq,
    const unsigned short* __restrict__ w1,
    const float* __restrict__ bk, const float* __restrict__ bq,
    const float* __restrict__ b1,
    unsigned short* __restrict__ ko, unsigned short* __restrict__ qo,
    unsigned short* __restrict__ v1o) {
  const int lane = threadIdx.x & 63;
  const int wid  = blockIdx.x * 4 + (threadIdx.x >> 6);   // 2048 waves
  const int b  = wid >> 9;
  const int r  = wid & 511;
  const int hh = r >> 8;          // same for all 4 waves of a block
  const int nt = r & 255;         // consecutive across block waves
  const int n0 = nt * 16;
  const int m  = lane & 15;
  const int q  = lane >> 4;

  const unsigned short* xrow = xt + ((size_t)(b * N_) + n0 + m) * C_;
  const unsigned short* Ws[3] = {wk, wq, w1};

  floatx4 acc[3][8];
  const floatx4 z = {0.f, 0.f, 0.f, 0.f};
#pragma unroll
  for (int o = 0; o < 3; ++o)
#pragma unroll
    for (int tt = 0; tt < 8; ++tt) acc[o][tt] = z;

  for (int cs = 0; cs < 8; ++cs) {
    const int cb = cs * 32 + q * 8;
    short8 af = *reinterpret_cast<const short8*>(xrow + cb);
#pragma unroll
    for (int o = 0; o < 3; ++o) {
#pragma unroll
      for (int tt = 0; tt < 8; ++tt) {
        const int h0 = (hh * 8 + tt) * 16;
        short8 bf = *reinterpret_cast<const short8*>(Ws[o] + (h0 + m) * C_ + cb);
        acc[o][tt] = mfma16(af, bf, acc[o][tt]);
      }
    }
  }

  // k: chunk-tiled store
#pragma unroll
  for (int tt = 0; tt < 8; ++tt) {
    const int ks16 = hh * 8 + tt;
    const float bias = bk[ks16 * 16 + m];
#pragma unroll
    for (int r2 = 0; r2 < 4; ++r2) {
      const int n = n0 + q * 4 + r2;
      ko[((size_t)(b * 128 + (n >> 5))) * 8192 + ks16 * 512 + (n & 31) * 16 + m] =
          f2bf(acc[0][tt][r2] + bias);
    }
  }
  // q, v1: linear stores
  const float* biases[2] = {bq, b1};
  unsigned short* outs[2] = {qo, v1o};
#pragma unroll
  for (int o = 0; o < 2; ++o) {
#pragma unroll
    for (int tt = 0; tt < 8; ++tt) {
      const int h0 = (hh * 8 + tt) * 16;
      const float bias = biases[o][h0 + m];
#pragma unroll
      for (int r2 = 0; r2 < 4; ++r2) {
        const int n = n0 + q * 4 + r2;
        outs[o][(b * N_ + n) * H_ + h0 + m] = f2bf(acc[o + 1][tt][r2] + bias);
      }
    }
  }
}

// ---------------------------------------------------------------------------
// FUSED conv + gemm2. Block = (b, n-span32). v2 tile lives only in LDS [n][h].
// v output -> chunk-tiled [b][nc][kn2][o256][n16].
__global__ __launch_bounds__(256) void convgemm2_kernel(
    const unsigned short* __restrict__ v1, const float* __restrict__ W2,
    const float* __restrict__ b2, const unsigned short* __restrict__ w3,
    const float* __restrict__ b3, unsigned short* __restrict__ vo) {
  __shared__ unsigned short v2L[32][264];   // 16.5 KB, row pad 8

  const int h   = threadIdx.x;
  const int blk = blockIdx.x;        // 512
  const int b   = blk >> 7;
  const int nc  = blk & 127;
  const int n0  = nc * 32;
  const int g8  = h & ~7;

  {  // conv: sliding window, thread = h
    float w[24];
#pragma unroll
    for (int i = 0; i < 24; ++i) w[i] = W2[h * 24 + i];
    const float bias = b2[h];
    const unsigned short* vb = v1 + (size_t)b * (N_ * H_) + g8;

    float fp[8], fc[8], fn[8];
    if (n0 == 0) {
#pragma unroll
      for (int i = 0; i < 8; ++i) fp[i] = 0.f;
    } else {
      short8 u = *reinterpret_cast<const short8*>(vb + (size_t)(n0 - 1) * H_);
#pragma unroll
      for (int i = 0; i < 8; ++i) fp[i] = bf2f((unsigned short)u[i]);
    }
    {
      short8 u = *reinterpret_cast<const short8*>(vb + (size_t)n0 * H_);
#pragma unroll
      for (int i = 0; i < 8; ++i) fc[i] = bf2f((unsigned short)u[i]);
    }
#pragma unroll 1
    for (int ns = 0; ns < 32; ++ns) {
      const int n = n0 + ns;
      if (n + 1 < N_) {
        short8 u = *reinterpret_cast<const short8*>(vb + (size_t)(n + 1) * H_);
#pragma unroll
        for (int i = 0; i < 8; ++i) fn[i] = bf2f((unsigned short)u[i]);
      } else {
#pragma unroll
        for (int i = 0; i < 8; ++i) fn[i] = 0.f;
      }
      float a = bias;
#pragma unroll
      for (int i = 0; i < 8; ++i)
        a += w[i * 3] * fp[i] + w[i * 3 + 1] * fc[i] + w[i * 3 + 2] * fn[i];
      v2L[ns][h] = f2bf(fmaxf(a, 0.f));
#pragma unroll
      for (int i = 0; i < 8; ++i) { fp[i] = fc[i]; fc[i] = fn[i]; }
    }
  }
  __syncthreads();

  // gemm2: wave wv handles o-range wv*64..+63.  A = W3 rows o, B = v2L cols n.
  const int ln = threadIdx.x & 63;
  const int wv = threadIdx.x >> 6;
  const int m  = ln & 31;
  const int hl = ln >> 5;

  floatx16 acc2[2];
#pragma unroll
  for (int ot = 0; ot < 2; ++ot)
#pragma unroll
    for (int r = 0; r < 16; ++r) acc2[ot][r] = 0.f;

#pragma unroll
  for (int ks = 0; ks < 16; ++ks) {
    short8 bfr = *reinterpret_cast<const short8*>(&v2L[m][ks * 16 + hl * 8]);
#pragma unroll
    for (int ot = 0; ot < 2; ++ot) {
      const int o0 = wv * 64 + ot * 32;
      short8 afr = *reinterpret_cast<const short8*>(
          w3 + (o0 + m) * H_ + ks * 16 + hl * 8);
      acc2[ot] = mfma32(afr, bfr, acc2[ot]);
    }
  }

  const int kn  = (m >> 4) & 1;
  const int nlo = m & 15;
  unsigned short* vc = vo + ((size_t)(b * 128 + nc) * 2 + kn) * 4096 + nlo;
#pragma unroll
  for (int ot = 0; ot < 2; ++ot)
#pragma unroll
    for (int r = 0; r < 16; ++r) {
      const int o = wv * 64 + ot * 32 + (r & 3) + 8 * (r >> 2) + 4 * hl;
      vc[o * 16] = f2bf(acc2[ot][r] + b3[o]);
    }
}

// ---------------------------------------------------------------------------
// attn: m32/wave, 4 waves share staged K/V chunk, NSPLIT=4.
// Tail: last-finishing block per (b,mt128) group combines the 4 splits.
__global__ __launch_bounds__(256, 2) void attn_kernel(
    const unsigned short* __restrict__ kbf, const unsigned short* __restrict__ qbf,
    const unsigned short* __restrict__ vbf,
    unsigned short* __restrict__ pacc, float* __restrict__ pml,
    unsigned int* __restrict__ cnt, float* __restrict__ out) {
  __shared__ __attribute__((aligned(16))) char smem[2][32768];

  const int ln  = threadIdx.x & 63;
  const int wv  = threadIdx.x >> 6;
  const int gid = blockIdx.x;          // 512
  const int b   = gid & 3;             // low bits -> XCD spread of (b,s)
  const int s   = (gid >> 2) & 3;
  const int mt128 = gid >> 4;          // 0..31
  const int mt32  = mt128 * 4 + wv;    // 0..127
  const int m0  = mt32 * 32;
  const int m   = ln & 31;
  const int hl  = ln >> 5;
  const int lane_base = m * 32 + hl * 16;

  // Q frags: col m = lane&31, k = ks*16 + hl*8 + j
  const unsigned short* qrow = qbf + ((size_t)b * N_ + m0 + m) * H_ + hl * 8;
  short8 qf[16];
#pragma unroll
  for (int ks = 0; ks < 16; ++ks)
    qf[ks] = *reinterpret_cast<const short8*>(qrow + ks * 16);

  floatx16 acc[8];
#pragma unroll
  for (int t = 0; t < 8; ++t)
#pragma unroll
    for (int r = 0; r < 16; ++r) acc[t][r] = 0.f;
  float Lp = 0.f;

  auto stage = [&](int bfi, int nc) {
    const size_t row = (size_t)(b * 128 + s * 32 + nc);
    const char* kg = (const char*)(kbf + row * 8192);
    const char* vg = (const char*)(vbf + row * 8192);
    char* lk = &smem[bfi][0];
    char* lv = &smem[bfi][16384];
#pragma unroll
    for (int j = 0; j < 4; ++j) {
      const int ofs = j * 4096 + wv * 1024 + ln * 16;
      __builtin_amdgcn_global_load_lds(
          (const __attribute__((address_space(1))) void*)(kg + ofs),
          (__attribute__((address_space(3))) void*)(lk + ofs), 16, 0, 0);
      __builtin_amdgcn_global_load_lds(
          (const __attribute__((address_space(1))) void*)(vg + ofs),
          (__attribute__((address_space(3))) void*)(lv + ofs), 16, 0, 0);
    }
  };

  stage(0, 0);
  int bufi = 0;

#pragma unroll 1
  for (int nc = 0; nc < ITERS; ++nc) {
    __syncthreads();                    // drains this chunk's staging
    if (nc + 1 < ITERS) stage(bufi ^ 1, nc + 1);

    const char* sk = &smem[bufi][0];
    const char* sv = &smem[bufi][16384];

    // S tile 32n x 32m: A = K rows from LDS, B = qf
    floatx16 sacc;
#pragma unroll
    for (int r = 0; r < 16; ++r) sacc[r] = 0.f;
#pragma unroll
    for (int ks = 0; ks < 16; ++ks) {
      short8 kf = *reinterpret_cast<const short8*>(sk + lane_base + ks * 1024);
      sacc = mfma32(kf, qf[ks], sacc);
    }

    short8 pf0, pf1;
#if __has_builtin(__builtin_amdgcn_permlane32_swap)
    // P = exp(S), pack ADJACENT-n pairs: d[i] = (p[2i], p[2i+1])
    // lane (m,hl) reg r holds row n = (r&3)+8*(r>>2)+4*hl, so
    // d0=(n0,n1) d1=(n2,n3) d2=(n8,n9) d3=(n10,n11) (+4hl), d4..d7 for n16..27
    unsigned d[8];
#pragma unroll
    for (int i = 0; i < 8; ++i) {
      const float a = __expf(sacc[2 * i]);
      const float bb = __expf(sacc[2 * i + 1]);
      Lp += a + bb;
      d[i] = pack2bf(a, bb);
    }
    // B-frag kn: dwords [d0',d1',d2',d3'] with (d0',d2')=plswap(d0,d2) etc.
#pragma unroll
    for (int g = 0; g < 2; ++g) {
      uint2v r0 = __builtin_amdgcn_permlane32_swap(d[4 * g + 0], d[4 * g + 2],
                                                   false, false);
      uint2v r1 = __builtin_amdgcn_permlane32_swap(d[4 * g + 1], d[4 * g + 3],
                                                   false, false);
      d[4 * g + 0] = r0.x; d[4 * g + 2] = r0.y;
      d[4 * g + 1] = r1.x; d[4 * g + 3] = r1.y;
    }
    union { unsigned u[4]; short8 s8; } c0, c1;
    c0.u[0] = d[0]; c0.u[1] = d[1]; c0.u[2] = d[2]; c0.u[3] = d[3];
    c1.u[0] = d[4]; c1.u[1] = d[5]; c1.u[2] = d[6]; c1.u[3] = d[7];
    pf0 = c0.s8;
    pf1 = c1.s8;
#else
    // fallback: pack (r, r+4) pairs + 16 bpermute relayout (R6 path)
    float pv[16];
#pragma unroll
    for (int r = 0; r < 16; ++r) { pv[r] = __expf(sacc[r]); Lp += pv[r]; }
    unsigned wpk[8];
#pragma unroll
    for (int r4 = 0; r4 < 4; ++r4) {
      wpk[r4]     = pack2bf(pv[r4], pv[r4 + 4]);
      wpk[r4 + 4] = pack2bf(pv[r4 + 8], pv[r4 + 12]);
    }
    const int hlsh = hl * 16;
#pragma unroll
    for (int j = 0; j < 8; ++j) {
      const int srcLane = m + ((j >> 2) << 5);
      const int u0 = __shfl((int)wpk[j & 3],       srcLane);
      const int u1 = __shfl((int)wpk[(j & 3) + 4], srcLane);
      pf0[j] = (short)((unsigned)u0 >> hlsh);
      pf1[j] = (short)((unsigned)u1 >> hlsh);
    }
#endif

    // PV: D[o][m] += V-rows (A, from LDS) * P (B, regs)
#pragma unroll
    for (int ot = 0; ot < 8; ++ot) {
      short8 vf0 = *reinterpret_cast<const short8*>(sv + lane_base + ot * 1024);
      short8 vf1 = *reinterpret_cast<const short8*>(
          sv + lane_base + 8192 + ot * 1024);
      acc[ot] = mfma32(vf0, pf0, acc[ot]);
      acc[ot] = mfma32(vf1, pf1, acc[ot]);
    }
    bufi ^= 1;
  }

  // epilogue: column sum across halves, normalize, store bf16 partial + L
  float Lv = Lp + __shfl_xor(Lp, 32);
  const float invL = 1.f / Lv;

  const int pwid = (b * 128 + mt32) * NSPLIT + s;
  unsigned short* pa = pacc + (size_t)pwid * (O_ * 32);
#pragma unroll
  for (int ot = 0; ot < 8; ++ot)
#pragma unroll
    for (int r = 0; r < 16; ++r) {
      const int o = ot * 32 + (r & 3) + 8 * (r >> 2) + 4 * hl;
      pa[o * 32 + m] = f2bf(acc[ot][r] * invL);
    }
  if (hl == 0) pml[pwid * 32 + m] = Lv;

  // ---- fused split-combine: last block of the (b, mt128) group merges ----
  __syncthreads();   // all partial stores issued; smem reusable
  int* sflag = (int*)&smem[0][0];
  float* wsm = (float*)&smem[0][64];   // 4 waves x 128 floats
  if (threadIdx.x == 0) {
    __threadfence();                   // publish pacc/pml device-wide
    sflag[0] = (int)atomicAdd(&cnt[b * 32 + mt128], 1u);
  }
  __syncthreads();
  if (sflag[0] != NSPLIT - 1) return;
  __threadfence();                     // acquire other splits' writes

  const int base4 = (b * 128 + mt32) * NSPLIT;
  if (hl == 0) {                       // lanes 0..31: per-column weights
    const int c = ln;
    float L[NSPLIT], sum = 0.f;
#pragma unroll
    for (int sp = 0; sp < NSPLIT; ++sp) {
      L[sp] = pml[(base4 + sp) * 32 + c];
      sum += L[sp];
    }
    const float inv = 1.f / sum;
#pragma unroll
    for (int sp = 0; sp < NSPLIT; ++sp)
      wsm[wv * 128 + sp * 32 + c] = L[sp] * inv;
  }
  const int m8 = (ln & 3) * 8;
  float wreg[NSPLIT][8];
#pragma unroll
  for (int sp = 0; sp < NSPLIT; ++sp)
#pragma unroll
    for (int i = 0; i < 8; ++i)
      wreg[sp][i] = wsm[wv * 128 + sp * 32 + m8 + i];

#pragma unroll 1
  for (int ot = 0; ot < 16; ++ot) {
    const int orow = ot * 16 + (ln >> 2);
    float res[8];
#pragma unroll
    for (int i = 0; i < 8; ++i) res[i] = 0.f;
#pragma unroll
    for (int sp = 0; sp < NSPLIT; ++sp) {
      short8 u = *reinterpret_cast<const short8*>(
          pacc + (size_t)(base4 + sp) * (O_ * 32) + orow * 32 + m8);
#pragma unroll
      for (int i = 0; i < 8; ++i)
        res[i] = fmaf(wreg[sp][i], bf2f((unsigned short)u[i]), res[i]);
    }
    float* op = out + ((size_t)(b * O_) + orow) * N_ + mt32 * 32 + m8;
    floatx4 v0 = {res[0], res[1], res[2], res[3]};
    floatx4 v1 = {res[4], res[5], res[6], res[7]};
    *reinterpret_cast<floatx4*>(op) = v0;
    *reinterpret_cast<floatx4*>(op + 4) = v1;
  }
}

// ---------------------------------------------------------------------------
extern "C" void kernel_launch(void* const* d_in, const int* in_sizes, int n_in,
                              void* d_out, int out_size, void* d_ws, size_t ws_size,
                              hipStream_t stream) {
  const float* x  = (const float*)d_in[0];
  const float* Wk = (const float*)d_in[1];
  const float* bk = (const float*)d_in[2];
  const float* Wq = (const float*)d_in[3];
  const float* bq = (const float*)d_in[4];
  const float* W1 = (const float*)d_in[5];
  const float* b1 = (const float*)d_in[6];
  const float* W2 = (const float*)d_in[7];
  const float* b2 = (const float*)d_in[8];
  const float* W3 = (const float*)d_in[9];
  const float* b3 = (const float*)d_in[10];
  float* out = (float*)d_out;

  char* ws = (char*)d_ws;
  const size_t SZ = (size_t)B_ * N_ * H_ * sizeof(unsigned short);  // 8 MiB
  unsigned short* wkbf = (unsigned short*)(ws);
  unsigned short* wqbf = (unsigned short*)(ws + 131072);
  unsigned short* w1bf = (unsigned short*)(ws + 262144);
  unsigned short* w3bf = (unsigned short*)(ws + 393216);
  char* base = ws + 524288;
  unsigned short* kbf  = (unsigned short*)(base);           // persistent (tiled)
  unsigned short* qbf  = (unsigned short*)(base + SZ);      // persistent
  unsigned short* vbf  = (unsigned short*)(base + 2 * SZ);  // persistent (tiled)
  unsigned short* xtbf = (unsigned short*)(base + 3 * SZ);  // dead after gemm1
  unsigned short* v1bf = (unsigned short*)(base + 4 * SZ);  // dead after cg2
  // partials (32 MB = 4*SZ) overlap xt/v1 + 2 more SZ
  unsigned short* pacc = (unsigned short*)(base + 3 * SZ);
  float*          pml  = (float*)(base + 7 * SZ);           // 256 KB
  unsigned int*   cnt  = (unsigned int*)(base + 7 * SZ + 262144);  // 512 B

  prep_transpose_kernel<<<1280, 256, 0, stream>>>(
      x, xtbf, Wk, Wq, W1, W3, wkbf, wqbf, w1bf, w3bf, cnt);
  gemm1_kernel<<<512, 256, 0, stream>>>(xtbf, wkbf, wqbf, w1bf, bk, bq, b1,
                                        kbf, qbf, v1bf);
  convgemm2_kernel<<<512, 256, 0, stream>>>(v1bf, W2, b2, w3bf, b3, vbf);
  attn_kernel<<<512, 256, 0, stream>>>(kbf, qbf, vbf, pacc, pml, cnt, out);
}

// Round 8
// 248.140 us; speedup vs baseline: 1.1211x; 1.1211x over previous
//
#include <hip/hip_runtime.h>

// ============================================================================
// global_conv_attn: B=4, C=H=O=256, N=4096, GROUPS=32
//
// Pipeline (all bf16-MFMA, fp32 accumulate), 5 launches:
//   prepT: weights fp32->bf16 (256 blocks) + x transpose (1024 blocks)
//   gemm1: k/qT/v1 = xt * W^T + bias; q,v1 linear [b][n][h];
//          k CHUNK-TILED [b][nc][ks16][n32][h-granule^((n>>2)&1)][h8]
//   cg2  : FUSED conv+gemm2; v CHUNK-TILED [b][nc][kn2][o256][n-gran^((o>>2)&1)]
//   attn : flash, 32x32x16 MFMA, m32/wave, 4 waves share staged K/V chunk,
//          NSPLIT=4, dbuf global_load_lds, constant-shift softmax,
//          P relayout via v_permlane32_swap; BANK-SWIZZLED lane_base
//   comb : standalone merge of 4 splits (R7's fused version made a 45us
//          serialized 128-block tail -- reverted)
//
// R7 post-mortem: fused combine tail +46us (FETCH +15MB inside attn, occ
// 20->14%). NEW: K/V LDS image had 8-way bank conflicts on ALL frag reads
// (granule (2m+hl)&7; SQ_LDS_BANK_CONFLICT pinned at 8.39e6 since R4).
// R8: XOR-swizzle granule by bit2-of-row in the GLOBAL layouts (staging is
// linear lane*16, so swizzle must be pre-baked) -> 4-way (~free-ish).
//
// MFMA 32x32x16 layouts (gfx950):
//   A row=lane&31, k=(lane>>5)*8+j;  B col=lane&31, same k
//   D col=lane&31, row=(reg&3)+8*(reg>>2)+4*(lane>>5)   [D HW-verified]
// ============================================================================

#define B_ 4
#define C_ 256
#define H_ 256
#define O_ 256
#define N_ 4096
#define NSPLIT 4
#define SPAN (N_ / NSPLIT)     // 1024
#define ITERS (SPAN / 32)      // 32

typedef short short8 __attribute__((ext_vector_type(8)));
typedef float floatx4 __attribute__((ext_vector_type(4)));
typedef float floatx16 __attribute__((ext_vector_type(16)));
typedef unsigned uint2v __attribute__((ext_vector_type(2)));

__device__ __forceinline__ unsigned short f2bf(float f) {
  unsigned u = __float_as_uint(f);
  u = (u + 0x7fffu + ((u >> 16) & 1u)) >> 16;   // RNE
  return (unsigned short)u;
}
__device__ __forceinline__ float bf2f(unsigned short u) {
  return __uint_as_float(((unsigned)u) << 16);
}
__device__ __forceinline__ floatx4 mfma16(short8 a, short8 b, floatx4 c) {
  return __builtin_amdgcn_mfma_f32_16x16x32_bf16(a, b, c, 0, 0, 0);
}
__device__ __forceinline__ floatx16 mfma32(short8 a, short8 b, floatx16 c) {
  return __builtin_amdgcn_mfma_f32_32x32x16_bf16(a, b, c, 0, 0, 0);
}
// pack two floats -> (bf16(a) | bf16(b)<<16), round-half-up (2 add + 1 perm)
__device__ __forceinline__ unsigned pack2bf(float a, float b) {
  return __builtin_amdgcn_perm(__float_as_uint(b) + 0x8000u,
                               __float_as_uint(a) + 0x8000u, 0x07060302u);
}

// ---------------------------------------------------------------------------
// merged weight prep (blocks 1024..1279) + x transpose (blocks 0..1023)
__global__ __launch_bounds__(256) void prep_transpose_kernel(
    const float* __restrict__ x, unsigned short* __restrict__ xt,
    const float* __restrict__ Wk, const float* __restrict__ Wq,
    const float* __restrict__ W1, const float* __restrict__ W3,
    unsigned short* __restrict__ wk, unsigned short* __restrict__ wq,
    unsigned short* __restrict__ w1, unsigned short* __restrict__ w3) {
  __shared__ unsigned short tile[64][66];
  const int gid = blockIdx.x;     // 1280
  const int t = threadIdx.x;
  if (gid >= 1024) {              // weight prep
    const int i = (gid - 1024) * 256 + t;    // 65536
    wk[i] = f2bf(Wk[i]);
    wq[i] = f2bf(Wq[i]);
    w1[i] = f2bf(W1[i]);
    w3[i] = f2bf(W3[i]);
    return;
  }
  const int b  = gid >> 8;
  const int ct = (gid >> 6) & 3;
  const int nt = gid & 63;
  const int c0 = ct * 64, n0 = nt * 64;
  const float* xb = x + ((size_t)b * C_ + c0) * N_ + n0;
#pragma unroll
  for (int rr = 0; rr < 4; ++rr) {
    const int c = (t >> 4) + rr * 16;
    const floatx4 v = *reinterpret_cast<const floatx4*>(
        xb + (size_t)c * N_ + (t & 15) * 4);
#pragma unroll
    for (int i = 0; i < 4; ++i) tile[c][(t & 15) * 4 + i] = f2bf(v[i]);
  }
  __syncthreads();
  unsigned short* xo = xt + ((size_t)b * N_ + n0) * C_ + c0;
#pragma unroll
  for (int rr = 0; rr < 2; ++rr) {
    const int nr = (t >> 3) + rr * 32;
    short8 pk;
#pragma unroll
    for (int i = 0; i < 8; ++i) pk[i] = (short)tile[(t & 7) * 8 + i][nr];
    *reinterpret_cast<short8*>(xo + (size_t)nr * C_ + (t & 7) * 8) = pk;
  }
}

// ---------------------------------------------------------------------------
// gemm1: D[n][h] = sum_c xt[n][c] * W[h][c] + bias[h], for Wk,Wq,W1.
// k -> chunk-tiled [b][n>>5][h>>4][n&31][h&15], h-granule XOR (n>>2)&1.
// Block waves share h-half -> W B-frags L1-resident across waves.
__global__ __launch_bounds__(256) void gemm1_kernel(
    const unsigned short* __restrict__ xt,
    const unsigned short* __restrict__ wk, const unsigned short* __restrict__ wq,
    const unsigned short* __restrict__ w1,
    const float* __restrict__ bk, const float* __restrict__ bq,
    const float* __restrict__ b1,
    unsigned short* __restrict__ ko, unsigned short* __restrict__ qo,
    unsigned short* __restrict__ v1o) {
  const int lane = threadIdx.x & 63;
  const int wid  = blockIdx.x * 4 + (threadIdx.x >> 6);   // 2048 waves
  const int b  = wid >> 9;
  const int r  = wid & 511;
  const int hh = r >> 8;          // same for all 4 waves of a block
  const int nt = r & 255;         // consecutive across block waves
  const int n0 = nt * 16;
  const int m  = lane & 15;
  const int q  = lane >> 4;

  const unsigned short* xrow = xt + ((size_t)(b * N_) + n0 + m) * C_;
  const unsigned short* Ws[3] = {wk, wq, w1};

  floatx4 acc[3][8];
  const floatx4 z = {0.f, 0.f, 0.f, 0.f};
#pragma unroll
  for (int o = 0; o < 3; ++o)
#pragma unroll
    for (int tt = 0; tt < 8; ++tt) acc[o][tt] = z;

  for (int cs = 0; cs < 8; ++cs) {
    const int cb = cs * 32 + q * 8;
    short8 af = *reinterpret_cast<const short8*>(xrow + cb);
#pragma unroll
    for (int o = 0; o < 3; ++o) {
#pragma unroll
      for (int tt = 0; tt < 8; ++tt) {
        const int h0 = (hh * 8 + tt) * 16;
        short8 bf = *reinterpret_cast<const short8*>(Ws[o] + (h0 + m) * C_ + cb);
        acc[o][tt] = mfma16(af, bf, acc[o][tt]);
      }
    }
  }

  // k: chunk-tiled store with bank swizzle: h-elem m ^ (((n>>2)&1)<<3).
  // n = n0 + q*4 + r2 -> (n>>2)&1 = q&1 (lane-constant).
  const int msw = m ^ ((q & 1) << 3);
#pragma unroll
  for (int tt = 0; tt < 8; ++tt) {
    const int ks16 = hh * 8 + tt;
    const float bias = bk[ks16 * 16 + m];
#pragma unroll
    for (int r2 = 0; r2 < 4; ++r2) {
      const int n = n0 + q * 4 + r2;
      ko[((size_t)(b * 128 + (n >> 5))) * 8192 + ks16 * 512 + (n & 31) * 16 + msw] =
          f2bf(acc[0][tt][r2] + bias);
    }
  }
  // q, v1: linear stores
  const float* biases[2] = {bq, b1};
  unsigned short* outs[2] = {qo, v1o};
#pragma unroll
  for (int o = 0; o < 2; ++o) {
#pragma unroll
    for (int tt = 0; tt < 8; ++tt) {
      const int h0 = (hh * 8 + tt) * 16;
      const float bias = biases[o][h0 + m];
#pragma unroll
      for (int r2 = 0; r2 < 4; ++r2) {
        const int n = n0 + q * 4 + r2;
        outs[o][(b * N_ + n) * H_ + h0 + m] = f2bf(acc[o + 1][tt][r2] + bias);
      }
    }
  }
}

// ---------------------------------------------------------------------------
// FUSED conv + gemm2. Block = (b, n-span32). v2 tile lives only in LDS [n][h].
// v -> chunk-tiled [b][nc][kn2][o256][n16], n-granule XOR (o>>2)&1 (= hl).
__global__ __launch_bounds__(256) void convgemm2_kernel(
    const unsigned short* __restrict__ v1, const float* __restrict__ W2,
    const float* __restrict__ b2, const unsigned short* __restrict__ w3,
    const float* __restrict__ b3, unsigned short* __restrict__ vo) {
  __shared__ unsigned short v2L[32][264];   // 16.5 KB, row pad 8

  const int h   = threadIdx.x;
  const int blk = blockIdx.x;        // 512
  const int b   = blk >> 7;
  const int nc  = blk & 127;
  const int n0  = nc * 32;
  const int g8  = h & ~7;

  {  // conv: sliding window, thread = h
    float w[24];
#pragma unroll
    for (int i = 0; i < 24; ++i) w[i] = W2[h * 24 + i];
    const float bias = b2[h];
    const unsigned short* vb = v1 + (size_t)b * (N_ * H_) + g8;

    float fp[8], fc[8], fn[8];
    if (n0 == 0) {
#pragma unroll
      for (int i = 0; i < 8; ++i) fp[i] = 0.f;
    } else {
      short8 u = *reinterpret_cast<const short8*>(vb + (size_t)(n0 - 1) * H_);
#pragma unroll
      for (int i = 0; i < 8; ++i) fp[i] = bf2f((unsigned short)u[i]);
    }
    {
      short8 u = *reinterpret_cast<const short8*>(vb + (size_t)n0 * H_);
#pragma unroll
      for (int i = 0; i < 8; ++i) fc[i] = bf2f((unsigned short)u[i]);
    }
#pragma unroll 1
    for (int ns = 0; ns < 32; ++ns) {
      const int n = n0 + ns;
      if (n + 1 < N_) {
        short8 u = *reinterpret_cast<const short8*>(vb + (size_t)(n + 1) * H_);
#pragma unroll
        for (int i = 0; i < 8; ++i) fn[i] = bf2f((unsigned short)u[i]);
      } else {
#pragma unroll
        for (int i = 0; i < 8; ++i) fn[i] = 0.f;
      }
      float a = bias;
#pragma unroll
      for (int i = 0; i < 8; ++i)
        a += w[i * 3] * fp[i] + w[i * 3 + 1] * fc[i] + w[i * 3 + 2] * fn[i];
      v2L[ns][h] = f2bf(fmaxf(a, 0.f));
#pragma unroll
      for (int i = 0; i < 8; ++i) { fp[i] = fc[i]; fc[i] = fn[i]; }
    }
  }
  __syncthreads();

  // gemm2: wave wv handles o-range wv*64..+63.  A = W3 rows o, B = v2L cols n.
  const int ln = threadIdx.x & 63;
  const int wv = threadIdx.x >> 6;
  const int m  = ln & 31;
  const int hl = ln >> 5;

  floatx16 acc2[2];
#pragma unroll
  for (int ot = 0; ot < 2; ++ot)
#pragma unroll
    for (int r = 0; r < 16; ++r) acc2[ot][r] = 0.f;

#pragma unroll
  for (int ks = 0; ks < 16; ++ks) {
    short8 bfr = *reinterpret_cast<const short8*>(&v2L[m][ks * 16 + hl * 8]);
#pragma unroll
    for (int ot = 0; ot < 2; ++ot) {
      const int o0 = wv * 64 + ot * 32;
      short8 afr = *reinterpret_cast<const short8*>(
          w3 + (o0 + m) * H_ + ks * 16 + hl * 8);
      acc2[ot] = mfma32(afr, bfr, acc2[ot]);
    }
  }

  // D rows = o, cols = n (lane&31). bank-swizzled chunk-tiled V store:
  // elem = o*16 + (nlo ^ (((o>>2)&1)<<3)); here (o>>2)&1 == hl.
  const int kn  = (m >> 4) & 1;
  const int nsw = (m & 15) ^ (hl << 3);
  unsigned short* vkn = vo + ((size_t)(b * 128 + nc) * 2 + kn) * 4096;
#pragma unroll
  for (int ot = 0; ot < 2; ++ot)
#pragma unroll
    for (int r = 0; r < 16; ++r) {
      const int o = wv * 64 + ot * 32 + (r & 3) + 8 * (r >> 2) + 4 * hl;
      vkn[o * 16 + nsw] = f2bf(acc2[ot][r] + b3[o]);
    }
}

// ---------------------------------------------------------------------------
// attn: m32/wave, 4 waves share staged K/V chunk, NSPLIT=4. Bank-swizzled
// lane_base; P relayout via permlane32_swap; writes normalized partials.
__global__ __launch_bounds__(256, 2) void attn_kernel(
    const unsigned short* __restrict__ kbf, const unsigned short* __restrict__ qbf,
    const unsigned short* __restrict__ vbf,
    unsigned short* __restrict__ pacc, float* __restrict__ pml) {
  __shared__ __attribute__((aligned(16))) char smem[2][32768];

  const int ln  = threadIdx.x & 63;
  const int wv  = threadIdx.x >> 6;
  const int gid = blockIdx.x;          // 512
  const int b   = gid & 3;             // low bits -> XCD spread of (b,s)
  const int s   = (gid >> 2) & 3;
  const int mt128 = gid >> 4;          // 0..31
  const int mt32  = mt128 * 4 + wv;    // 0..127
  const int m0  = mt32 * 32;
  const int m   = ln & 31;
  const int hl  = ln >> 5;
  // bank-swizzled fragment base: granule = hl ^ ((row>>2)&1), row = m
  const int lane_base = m * 32 + (hl ^ ((m >> 2) & 1)) * 16;

  // Q frags: col m = lane&31, k = ks*16 + hl*8 + j
  const unsigned short* qrow = qbf + ((size_t)b * N_ + m0 + m) * H_ + hl * 8;
  short8 qf[16];
#pragma unroll
  for (int ks = 0; ks < 16; ++ks)
    qf[ks] = *reinterpret_cast<const short8*>(qrow + ks * 16);

  floatx16 acc[8];
#pragma unroll
  for (int t = 0; t < 8; ++t)
#pragma unroll
    for (int r = 0; r < 16; ++r) acc[t][r] = 0.f;
  float Lp = 0.f;

  auto stage = [&](int bfi, int nc) {
    const size_t row = (size_t)(b * 128 + s * 32 + nc);
    const char* kg = (const char*)(kbf + row * 8192);
    const char* vg = (const char*)(vbf + row * 8192);
    char* lk = &smem[bfi][0];
    char* lv = &smem[bfi][16384];
#pragma unroll
    for (int j = 0; j < 4; ++j) {
      const int ofs = j * 4096 + wv * 1024 + ln * 16;
      __builtin_amdgcn_global_load_lds(
          (const __attribute__((address_space(1))) void*)(kg + ofs),
          (__attribute__((address_space(3))) void*)(lk + ofs), 16, 0, 0);
      __builtin_amdgcn_global_load_lds(
          (const __attribute__((address_space(1))) void*)(vg + ofs),
          (__attribute__((address_space(3))) void*)(lv + ofs), 16, 0, 0);
    }
  };

  stage(0, 0);
  int bufi = 0;

#pragma unroll 1
  for (int nc = 0; nc < ITERS; ++nc) {
    __syncthreads();                    // drains this chunk's staging
    if (nc + 1 < ITERS) stage(bufi ^ 1, nc + 1);

    const char* sk = &smem[bufi][0];
    const char* sv = &smem[bufi][16384];

    // S tile 32n x 32m: A = K rows from LDS, B = qf
    floatx16 sacc;
#pragma unroll
    for (int r = 0; r < 16; ++r) sacc[r] = 0.f;
#pragma unroll
    for (int ks = 0; ks < 16; ++ks) {
      short8 kf = *reinterpret_cast<const short8*>(sk + lane_base + ks * 1024);
      sacc = mfma32(kf, qf[ks], sacc);
    }

    short8 pf0, pf1;
#if __has_builtin(__builtin_amdgcn_permlane32_swap)
    // P = exp(S), pack ADJACENT-n pairs: d[i] = (p[2i], p[2i+1])
    unsigned d[8];
#pragma unroll
    for (int i = 0; i < 8; ++i) {
      const float a = __expf(sacc[2 * i]);
      const float bb = __expf(sacc[2 * i + 1]);
      Lp += a + bb;
      d[i] = pack2bf(a, bb);
    }
#pragma unroll
    for (int g = 0; g < 2; ++g) {
      uint2v r0 = __builtin_amdgcn_permlane32_swap(d[4 * g + 0], d[4 * g + 2],
                                                   false, false);
      uint2v r1 = __builtin_amdgcn_permlane32_swap(d[4 * g + 1], d[4 * g + 3],
                                                   false, false);
      d[4 * g + 0] = r0.x; d[4 * g + 2] = r0.y;
      d[4 * g + 1] = r1.x; d[4 * g + 3] = r1.y;
    }
    union { unsigned u[4]; short8 s8; } c0, c1;
    c0.u[0] = d[0]; c0.u[1] = d[1]; c0.u[2] = d[2]; c0.u[3] = d[3];
    c1.u[0] = d[4]; c1.u[1] = d[5]; c1.u[2] = d[6]; c1.u[3] = d[7];
    pf0 = c0.s8;
    pf1 = c1.s8;
#else
    // fallback: pack (r, r+4) pairs + 16 bpermute relayout (R6 path)
    float pv[16];
#pragma unroll
    for (int r = 0; r < 16; ++r) { pv[r] = __expf(sacc[r]); Lp += pv[r]; }
    unsigned wpk[8];
#pragma unroll
    for (int r4 = 0; r4 < 4; ++r4) {
      wpk[r4]     = pack2bf(pv[r4], pv[r4 + 4]);
      wpk[r4 + 4] = pack2bf(pv[r4 + 8], pv[r4 + 12]);
    }
    const int hlsh = hl * 16;
#pragma unroll
    for (int j = 0; j < 8; ++j) {
      const int srcLane = m + ((j >> 2) << 5);
      const int u0 = __shfl((int)wpk[j & 3],       srcLane);
      const int u1 = __shfl((int)wpk[(j & 3) + 4], srcLane);
      pf0[j] = (short)((unsigned)u0 >> hlsh);
      pf1[j] = (short)((unsigned)u1 >> hlsh);
    }
#endif

    // PV: D[o][m] += V-rows (A, from LDS) * P (B, regs)
#pragma unroll
    for (int ot = 0; ot < 8; ++ot) {
      short8 vf0 = *reinterpret_cast<const short8*>(sv + lane_base + ot * 1024);
      short8 vf1 = *reinterpret_cast<const short8*>(
          sv + lane_base + 8192 + ot * 1024);
      acc[ot] = mfma32(vf0, pf0, acc[ot]);
      acc[ot] = mfma32(vf1, pf1, acc[ot]);
    }
    bufi ^= 1;
  }

  // epilogue: column sum across halves, normalize, store bf16 partial + L
  float Lv = Lp + __shfl_xor(Lp, 32);
  const float invL = 1.f / Lv;

  const int pwid = (b * 128 + mt32) * NSPLIT + s;
  unsigned short* pa = pacc + (size_t)pwid * (O_ * 32);
#pragma unroll
  for (int ot = 0; ot < 8; ++ot)
#pragma unroll
    for (int r = 0; r < 16; ++r) {
      const int o = ot * 32 + (r & 3) + 8 * (r >> 2) + 4 * hl;
      pa[o * 32 + m] = f2bf(acc[ot][r] * invL);
    }
  if (hl == 0) pml[pwid * 32 + m] = Lv;
}

// ---------------------------------------------------------------------------
// combine: out[b][o][m0+c] = sum_s w[s][c]*pacc[s][o][c], w = L_s/sum(L)
__global__ __launch_bounds__(256) void combine_kernel(
    const unsigned short* __restrict__ pacc, const float* __restrict__ pml,
    float* __restrict__ out) {
  const int blk = blockIdx.x;   // 512
  const int b   = blk >> 7;
  const int mw  = blk & 127;
  const int o   = threadIdx.x;
  const int base = (b * 128 + mw) * NSPLIT;

  __shared__ float w[NSPLIT][32];
  if (threadIdx.x < 32) {
    const int c = threadIdx.x;
    float L[NSPLIT], sum = 0.f;
#pragma unroll
    for (int sp = 0; sp < NSPLIT; ++sp) {
      L[sp] = pml[(base + sp) * 32 + c];
      sum += L[sp];
    }
    const float inv = 1.f / sum;
#pragma unroll
    for (int sp = 0; sp < NSPLIT; ++sp) w[sp][c] = L[sp] * inv;
  }
  __syncthreads();

  float res[32];
#pragma unroll
  for (int c = 0; c < 32; ++c) res[c] = 0.f;
#pragma unroll
  for (int sp = 0; sp < NSPLIT; ++sp) {
    const unsigned short* pa =
        pacc + (size_t)(base + sp) * (O_ * 32) + o * 32;
#pragma unroll
    for (int c8 = 0; c8 < 4; ++c8) {
      short8 u = *reinterpret_cast<const short8*>(pa + c8 * 8);
#pragma unroll
      for (int i = 0; i < 8; ++i)
        res[c8 * 8 + i] =
            fmaf(w[sp][c8 * 8 + i], bf2f((unsigned short)u[i]), res[c8 * 8 + i]);
    }
  }
  float* ob = out + ((size_t)(b * O_ + o)) * N_ + mw * 32;
#pragma unroll
  for (int c4 = 0; c4 < 8; ++c4) {
    floatx4 v4 = {res[c4 * 4], res[c4 * 4 + 1], res[c4 * 4 + 2], res[c4 * 4 + 3]};
    *reinterpret_cast<floatx4*>(ob + c4 * 4) = v4;
  }
}

// ---------------------------------------------------------------------------
extern "C" void kernel_launch(void* const* d_in, const int* in_sizes, int n_in,
                              void* d_out, int out_size, void* d_ws, size_t ws_size,
                              hipStream_t stream) {
  const float* x  = (const float*)d_in[0];
  const float* Wk = (const float*)d_in[1];
  const float* bk = (const float*)d_in[2];
  const float* Wq = (const float*)d_in[3];
  const float* bq = (const float*)d_in[4];
  const float* W1 = (const float*)d_in[5];
  const float* b1 = (const float*)d_in[6];
  const float* W2 = (const float*)d_in[7];
  const float* b2 = (const float*)d_in[8];
  const float* W3 = (const float*)d_in[9];
  const float* b3 = (const float*)d_in[10];
  float* out = (float*)d_out;

  char* ws = (char*)d_ws;
  const size_t SZ = (size_t)B_ * N_ * H_ * sizeof(unsigned short);  // 8 MiB
  unsigned short* wkbf = (unsigned short*)(ws);
  unsigned short* wqbf = (unsigned short*)(ws + 131072);
  unsigned short* w1bf = (unsigned short*)(ws + 262144);
  unsigned short* w3bf = (unsigned short*)(ws + 393216);
  char* base = ws + 524288;
  unsigned short* kbf  = (unsigned short*)(base);           // persistent (tiled)
  unsigned short* qbf  = (unsigned short*)(base + SZ);      // persistent
  unsigned short* vbf  = (unsigned short*)(base + 2 * SZ);  // persistent (tiled)
  unsigned short* xtbf = (unsigned short*)(base + 3 * SZ);  // dead after gemm1
  unsigned short* v1bf = (unsigned short*)(base + 4 * SZ);  // dead after cg2
  // partials (32 MB = 4*SZ) overlap xt/v1 + 2 more SZ
  unsigned short* pacc = (unsigned short*)(base + 3 * SZ);
  float*          pml  = (float*)(base + 7 * SZ);           // 256 KB

  prep_transpose_kernel<<<1280, 256, 0, stream>>>(
      x, xtbf, Wk, Wq, W1, W3, wkbf, wqbf, w1bf, w3bf);
  gemm1_kernel<<<512, 256, 0, stream>>>(xtbf, wkbf, wqbf, w1bf, bk, bq, b1,
                                        kbf, qbf, v1bf);
  convgemm2_kernel<<<512, 256, 0, stream>>>(v1bf, W2, b2, w3bf, b3, vbf);
  attn_kernel<<<512, 256, 0, stream>>>(kbf, qbf, vbf, pacc, pml);
  combine_kernel<<<512, 256, 0, stream>>>(pacc, pml, out);
}